// Round 9
// baseline (141.931 us; speedup 1.0000x reference)
//
#include <hip/hip_runtime.h>
#include <hip/hip_bf16.h>

#define D_MODEL 1024
#define INNER   2048
#define NPROJ   4096   // 2*INNER
#define BSZ     2
#define LSEQ    1024
#define MROWS   (BSZ*LSEQ)  // 2048

#define CHUNK 32
#define WARM  48
#define NCHK  (LSEQ / CHUNK)   // 32

using short8   = __attribute__((ext_vector_type(8))) short;
using ushort8  = __attribute__((ext_vector_type(8))) unsigned short;
using f32x4    = __attribute__((ext_vector_type(4))) float;
typedef unsigned short ushort;

__device__ __forceinline__ ushort tobf(float x) {
    return (ushort)(__builtin_bit_cast(unsigned, x) >> 16);
}
__device__ __forceinline__ float frombf(ushort h) {
    return __builtin_bit_cast(float, ((unsigned)h) << 16);
}
__device__ __forceinline__ void glds16(const void* g, void* l) {
    __builtin_amdgcn_global_load_lds((const __attribute__((address_space(1))) void*)g,
                                     (__attribute__((address_space(3))) void*)l, 16, 0, 0);
}

// f32 row-major (N x K) -> bf16 hi/lo in FRAGMENT-LINEAR order (16x32 subtiles,
// lane l = (kchunk<<4)|row holds 8 elems).
template<int K>
__device__ __forceinline__ void split_chunk(const float* __restrict__ in,
                                            ushort* __restrict__ hi,
                                            ushort* __restrict__ lo, int c) {
    int l = c & 63, sub = c >> 6;
    constexpr int KT = K / 32;
    int kt = sub % KT, rt = sub / KT;
    const float* src = in + (size_t)(rt * 16 + (l & 15)) * K + kt * 32 + (l >> 4) * 8;
    ushort8 h, lw;
#pragma unroll
    for (int j = 0; j < 8; ++j) {
        float x = src[j];
        h[j]  = tobf(x);
        lw[j] = tobf(x - frombf(h[j]));
    }
    *reinterpret_cast<ushort8*>(&hi[(size_t)c * 8]) = h;
    *reinterpret_cast<ushort8*>(&lo[(size_t)c * 8]) = lw;
}

template<int K>
__global__ __launch_bounds__(256) void splitbf_frag(const float* __restrict__ in,
                                                    ushort* __restrict__ hi,
                                                    ushort* __restrict__ lo, int nchunks) {
    int c = blockIdx.x * 256 + threadIdx.x;
    if (c >= nchunks) return;
    split_chunk<K>(in, hi, lo, c);
}

// fused: split two K=1024 matrices (W_in and x) in one launch
__global__ __launch_bounds__(256) void splitbf2_k(
    const float* __restrict__ in1, ushort* __restrict__ hi1, ushort* __restrict__ lo1, int n1,
    const float* __restrict__ in2, ushort* __restrict__ hi2, ushort* __restrict__ lo2, int n2) {
    int c = blockIdx.x * 256 + threadIdx.x;
    if (c < n1) {
        split_chunk<D_MODEL>(in1, hi1, lo1, c);
    } else {
        int cc = c - n1;
        if (cc < n2) split_chunk<D_MODEL>(in2, hi2, lo2, cc);
    }
}

// ---------------------------------------------------------------------------
// GEMM1 (in_proj): C[2048,4096] = x * W_in^T, bf16x3, all operands pre-split.
// 512 thr / 8 waves (2Mx4N), tile 128x256, BK=32, 3-deep counted-vmcnt pipe.
// K-tile split into 3 balanced TERM-phases (hi*hi / hi*lo / lo*hi), each with
// 16 independent MFMAs, balanced ds_reads (8/4/4) and 2 glds issues.
// ---------------------------------------------------------------------------
__global__ __launch_bounds__(512, 1) void gemm1_8ph(
    const ushort* __restrict__ Agh, const ushort* __restrict__ Agl,
    const ushort* __restrict__ Bgh, const ushort* __restrict__ Bgl,
    float* __restrict__ C)
{
    constexpr int KT = D_MODEL / 32;   // 32
    constexpr int NT = D_MODEL / 32;   // 32 K-tiles
    __shared__ ushort Ah[3][4096], Al[3][4096];   // 128x32 bf16 per buf
    __shared__ ushort Bh[3][8192], Bl[3][8192];   // 256x32 bf16 per buf

    const int tid = threadIdx.x;
    const int wid = tid >> 6, lane = tid & 63;
    const int lm = lane & 15, lk = lane >> 4;

    int lin = blockIdx.y * 16 + blockIdx.x;
    int swz = (lin & 7) * 32 + (lin >> 3);        // XCD-aware, bijective (256%8==0)
    const int m0 = (swz >> 4) * 128, n0 = (swz & 15) * 256;
    const int wm = (wid >> 2) * 64, wn = (wid & 3) * 64;

    f32x4 acc[4][4] = {};

    auto issueB = [&](const ushort* __restrict__ src, ushort* dst, int t, int ci) {
        int s = wid + ci * 8;
        const ushort* g = src + ((size_t)((n0 >> 4) + s) * KT + t) * 512 + lane * 8;
        glds16(g, dst + s * 512);
    };
    auto issueA = [&](const ushort* __restrict__ src, ushort* dst, int t) {
        const ushort* g = src + ((size_t)((m0 >> 4) + wid) * KT + t) * 512 + lane * 8;
        glds16(g, dst + wid * 512);
    };
    auto stageTile = [&](int t, int b) {
        issueB(Bgh, &Bh[b][0], t, 0); issueB(Bgh, &Bh[b][0], t, 1);
        issueB(Bgl, &Bl[b][0], t, 0); issueB(Bgl, &Bl[b][0], t, 1);
        issueA(Agh, &Ah[b][0], t);    issueA(Agl, &Al[b][0], t);
    };

    stageTile(0, 0);
    stageTile(1, 1);
    asm volatile("s_waitcnt vmcnt(6)" ::: "memory");   // tile 0 landed
    __builtin_amdgcn_s_barrier();

    int cur = 0;
    for (int t = 0; t < NT; ++t) {
        int nx2 = cur + 2; if (nx2 >= 3) nx2 -= 3;
        const bool pf = (t + 2 < NT);
        short8 ah[4], al[4], bh[4], bl[4];

        // ---- phase A: hi*hi ---- (reads ah0-3, bh0-3; issues Bh t+2)
#pragma unroll
        for (int i = 0; i < 4; ++i) {
            int off = ((wm >> 4) + i) * 512 + lane * 8;
            ah[i] = *reinterpret_cast<const short8*>(&Ah[cur][off]);
        }
#pragma unroll
        for (int q = 0; q < 4; ++q) {
            int off = ((wn >> 4) + q) * 512 + lane * 8;
            bh[q] = *reinterpret_cast<const short8*>(&Bh[cur][off]);
        }
        if (pf) {
            issueB(Bgh, &Bh[nx2][0], t + 2, 0);
            issueB(Bgh, &Bh[nx2][0], t + 2, 1);
        }
        __builtin_amdgcn_s_barrier();
        asm volatile("s_waitcnt lgkmcnt(0)" ::: "memory");
        __builtin_amdgcn_sched_barrier(0);
        __builtin_amdgcn_s_setprio(1);
#pragma unroll
        for (int i = 0; i < 4; ++i)
#pragma unroll
            for (int q = 0; q < 4; ++q)
                acc[i][q] = __builtin_amdgcn_mfma_f32_16x16x32_bf16(ah[i], bh[q], acc[i][q], 0, 0, 0);
        __builtin_amdgcn_s_setprio(0);
        __builtin_amdgcn_s_barrier();

        // ---- phase B: hi*lo ---- (reads bl0-3; issues Bl t+2)
#pragma unroll
        for (int q = 0; q < 4; ++q) {
            int off = ((wn >> 4) + q) * 512 + lane * 8;
            bl[q] = *reinterpret_cast<const short8*>(&Bl[cur][off]);
        }
        if (pf) {
            issueB(Bgl, &Bl[nx2][0], t + 2, 0);
            issueB(Bgl, &Bl[nx2][0], t + 2, 1);
        }
        __builtin_amdgcn_s_barrier();
        asm volatile("s_waitcnt lgkmcnt(0)" ::: "memory");
        __builtin_amdgcn_sched_barrier(0);
        __builtin_amdgcn_s_setprio(1);
#pragma unroll
        for (int i = 0; i < 4; ++i)
#pragma unroll
            for (int q = 0; q < 4; ++q)
                acc[i][q] = __builtin_amdgcn_mfma_f32_16x16x32_bf16(ah[i], bl[q], acc[i][q], 0, 0, 0);
        __builtin_amdgcn_s_setprio(0);
        __builtin_amdgcn_s_barrier();

        // ---- phase C: lo*hi ---- (reads al0-3; issues A t+2; counted vmcnt)
#pragma unroll
        for (int i = 0; i < 4; ++i) {
            int off = ((wm >> 4) + i) * 512 + lane * 8;
            al[i] = *reinterpret_cast<const short8*>(&Al[cur][off]);
        }
        if (pf) {
            issueA(Agh, &Ah[nx2][0], t + 2);
            issueA(Agl, &Al[nx2][0], t + 2);
        }
        __builtin_amdgcn_s_barrier();
        asm volatile("s_waitcnt lgkmcnt(0)" ::: "memory");
        __builtin_amdgcn_sched_barrier(0);
        __builtin_amdgcn_s_setprio(1);
#pragma unroll
        for (int i = 0; i < 4; ++i)
#pragma unroll
            for (int q = 0; q < 4; ++q)
                acc[i][q] = __builtin_amdgcn_mfma_f32_16x16x32_bf16(al[i], bh[q], acc[i][q], 0, 0, 0);
        __builtin_amdgcn_s_setprio(0);
        if (pf) asm volatile("s_waitcnt vmcnt(6)" ::: "memory");
        else    asm volatile("s_waitcnt vmcnt(0)" ::: "memory");
        __builtin_amdgcn_s_barrier();
        cur = (cur == 2) ? 0 : cur + 1;
    }

#pragma unroll
    for (int i = 0; i < 4; ++i)
#pragma unroll
        for (int j = 0; j < 4; ++j)
#pragma unroll
            for (int r = 0; r < 4; ++r) {
                int row = m0 + wm + i * 16 + lk * 4 + r;
                int col = n0 + wn + j * 16 + lm;
                C[(size_t)row * NPROJ + col] = acc[i][j][r];
            }
}

// ---------------------------------------------------------------------------
// GEMM2 (out_proj): 2-phase bf16x3 with SPLIT-K. Grid (N/BN, M/BM, SPLITK);
// kz=0 writes C0 (d_out), kz>0 writes Crest[kz-1]; reduce_sk sums after.
// ---------------------------------------------------------------------------
template<int BM, int BN, int M, int N, int K, int SPLITK>
__global__ __launch_bounds__(256, 3) void gemm_mfma_sk(
    const ushort* __restrict__ Agh, const ushort* __restrict__ Agl,
    const ushort* __restrict__ Bgh, const ushort* __restrict__ Bgl,
    float* __restrict__ C0, float* __restrict__ Crest)
{
    constexpr int KT = K / 32;
    constexpr int NTL = KT / SPLITK;   // local K-tiles per block
    constexpr int FM = BM / 32;
    constexpr int FN = BN / 32;
    __shared__ ushort Ah[2][BM * 32], Al[2][BM * 32];
    __shared__ ushort Bh[2][BN * 32], Bl[2][BN * 32];

    const int tid = threadIdx.x;
    const int wid = tid >> 6, lane = tid & 63;
    const int lm = lane & 15, lk = lane >> 4;
    const int m0 = blockIdx.y * BM, n0 = blockIdx.x * BN;
    const int kz = blockIdx.z;
    const int t0 = kz * NTL;
    const int wm = (wid >> 1) * (BM / 2), wn = (wid & 1) * (BN / 2);

    f32x4 acc[FM][FN] = {};

    auto stage_frag = [&](const ushort* __restrict__ src, ushort* dst,
                          int rows, int rb, int tg) {
        const int nsub = rows >> 4;
        for (int s = wid; s < nsub; s += 4) {
            const ushort* g = src + ((size_t)((rb >> 4) + s) * KT + tg) * 512 + lane * 8;
            glds16(g, dst + s * 512);
        }
    };
    auto stageAll = [&](int t, int b) {
        stage_frag(Agh, &Ah[b][0], BM, m0, t0 + t);
        stage_frag(Agl, &Al[b][0], BM, m0, t0 + t);
        stage_frag(Bgh, &Bh[b][0], BN, n0, t0 + t);
        stage_frag(Bgl, &Bl[b][0], BN, n0, t0 + t);
    };
    auto compute = [&](int b) {
        short8 ah[FM], al[FM], bh[FN], bl[FN];
#pragma unroll
        for (int i = 0; i < FM; ++i) {
            int off = ((wm >> 4) + i) * 512 + lane * 8;
            ah[i] = *reinterpret_cast<const short8*>(&Ah[b][off]);
            al[i] = *reinterpret_cast<const short8*>(&Al[b][off]);
        }
#pragma unroll
        for (int j = 0; j < FN; ++j) {
            int off = ((wn >> 4) + j) * 512 + lane * 8;
            bh[j] = *reinterpret_cast<const short8*>(&Bh[b][off]);
            bl[j] = *reinterpret_cast<const short8*>(&Bl[b][off]);
        }
#pragma unroll
        for (int i = 0; i < FM; ++i)
#pragma unroll
            for (int j = 0; j < FN; ++j) {
                acc[i][j] = __builtin_amdgcn_mfma_f32_16x16x32_bf16(ah[i], bh[j], acc[i][j], 0, 0, 0);
                acc[i][j] = __builtin_amdgcn_mfma_f32_16x16x32_bf16(ah[i], bl[j], acc[i][j], 0, 0, 0);
                acc[i][j] = __builtin_amdgcn_mfma_f32_16x16x32_bf16(al[i], bh[j], acc[i][j], 0, 0, 0);
            }
    };

    stageAll(0, 0);
    __syncthreads();

    int buf = 0;
    for (int t = 0; t < NTL; ++t) {
        if (t + 1 < NTL) stageAll(t + 1, buf ^ 1);
        compute(buf);
        __syncthreads();
        buf ^= 1;
    }

    float* C = (kz == 0) ? C0 : (Crest + (size_t)(kz - 1) * M * N);
#pragma unroll
    for (int i = 0; i < FM; ++i)
#pragma unroll
        for (int j = 0; j < FN; ++j)
#pragma unroll
            for (int r = 0; r < 4; ++r) {
                int row = m0 + wm + i * 16 + lk * 4 + r;
                int col = n0 + wn + j * 16 + lm;
                C[(size_t)row * N + col] = acc[i][j][r];
            }
}

// out += sum of 3 partials (out already holds partial 0)
__global__ __launch_bounds__(256) void reduce_sk(float* __restrict__ out,
                                                 const float* __restrict__ rest) {
    constexpr size_t MN = (size_t)MROWS * D_MODEL;
    size_t i = ((size_t)blockIdx.x * 256 + threadIdx.x) * 4;
    f32x4 a = *reinterpret_cast<const f32x4*>(&out[i]);
    f32x4 b = *reinterpret_cast<const f32x4*>(&rest[i]);
    f32x4 c = *reinterpret_cast<const f32x4*>(&rest[MN + i]);
    f32x4 d = *reinterpret_cast<const f32x4*>(&rest[2 * MN + i]);
    *reinterpret_cast<f32x4*>(&out[i]) = (a + b) + (c + d);
}

// Chunk-parallel fused conv + sigmoid + scan + gate; emits yg as bf16 hi/lo
// in fragment-linear order for GEMM2's A (K = INNER = 2048, KT = 64).
__global__ __launch_bounds__(256) void scan_kernel(
    const float* __restrict__ xp,
    const float* __restrict__ conv_w, const float* __restrict__ conv_b,
    const float* __restrict__ Aa, const float* __restrict__ Bp, const float* __restrict__ Cp,
    ushort* __restrict__ yhi, ushort* __restrict__ ylo)
{
    const int NB = INNER / 256;  // 8
    int tid = threadIdx.x;
    int bi = blockIdx.x;
    int b  = bi / (NCHK * NB);
    int r  = bi % (NCHK * NB);
    int ch = r / NB;
    int n  = (r % NB) * 256 + tid;

    float4 w = *reinterpret_cast<const float4*>(&conv_w[n * 4]);
    float cb = conv_b[n];
    float An[16], Bn[16], Cn[16], st[16];
#pragma unroll
    for (int i = 0; i < 16; i += 4) {
        float4 va = *reinterpret_cast<const float4*>(&Aa[n * 16 + i]);
        float4 vb = *reinterpret_cast<const float4*>(&Bp[n * 16 + i]);
        float4 vc = *reinterpret_cast<const float4*>(&Cp[n * 16 + i]);
        An[i]=va.x; An[i+1]=va.y; An[i+2]=va.z; An[i+3]=va.w;
        Bn[i]=vb.x; Bn[i+1]=vb.y; Bn[i+2]=vb.z; Bn[i+3]=vb.w;
        Cn[i]=vc.x; Cn[i+1]=vc.y; Cn[i+2]=vc.z; Cn[i+3]=vc.w;
    }
#pragma unroll
    for (int s = 0; s < 16; ++s) st[s] = 0.f;

    int out0 = ch * CHUNK;
    int lstart = (out0 >= WARM) ? (out0 - WARM) : 0;
    float u0 = 0.f, u1 = 0.f, u2 = 0.f;
    const float* xb = xp + (size_t)b * LSEQ * NPROJ;
    size_t fcol = (size_t)(n >> 5) * 512 + ((n >> 3) & 3) * 128 + (n & 7);

    for (int l = lstart; l < out0; l += 8) {
        float uv[8];
#pragma unroll
        for (int i = 0; i < 8; ++i)
            uv[i] = xb[(size_t)(l + i) * NPROJ + 2 * n];
#pragma unroll
        for (int i = 0; i < 8; ++i) {
            float ul = uv[i];
            float xc = cb + w.x * u0 + w.y * u1 + w.z * u2 + w.w * ul;
            u0 = u1; u1 = u2; u2 = ul;
            float d = 1.f / (1.f + __expf(-xc));
            float dxc = d * xc;
#pragma unroll
            for (int s = 0; s < 16; ++s)
                st[s] = (An[s] * d) * st[s] + Bn[s] * dxc;
        }
    }
    for (int lt = 0; lt < CHUNK; lt += 8) {
        float uv[8], gv[8];
#pragma unroll
        for (int i = 0; i < 8; ++i) {
            float2 ug = *reinterpret_cast<const float2*>(
                &xb[(size_t)(out0 + lt + i) * NPROJ + 2 * n]);
            uv[i] = ug.x; gv[i] = ug.y;
        }
#pragma unroll
        for (int i = 0; i < 8; ++i) {
            float ul = uv[i];
            float xc = cb + w.x * u0 + w.y * u1 + w.z * u2 + w.w * ul;
            u0 = u1; u1 = u2; u2 = ul;
            float d = 1.f / (1.f + __expf(-xc));
            float dxc = d * xc;
            float y0 = 0.f, y1 = 0.f, y2 = 0.f, y3 = 0.f;
#pragma unroll
            for (int s = 0; s < 16; s += 4) {
                st[s + 0] = (An[s + 0] * d) * st[s + 0] + Bn[s + 0] * dxc;
                st[s + 1] = (An[s + 1] * d) * st[s + 1] + Bn[s + 1] * dxc;
                st[s + 2] = (An[s + 2] * d) * st[s + 2] + Bn[s + 2] * dxc;
                st[s + 3] = (An[s + 3] * d) * st[s + 3] + Bn[s + 3] * dxc;
                y0 += st[s + 0] * Cn[s + 0];
                y1 += st[s + 1] * Cn[s + 1];
                y2 += st[s + 2] * Cn[s + 2];
                y3 += st[s + 3] * Cn[s + 3];
            }
            float y = (y0 + y1) + (y2 + y3);
            float g = 1.f / (1.f + __expf(-gv[i]));
            float o = y * g;
            int R = b * LSEQ + out0 + lt + i;
            size_t fi = ((size_t)(R >> 4) * 64) * 512 + fcol + (R & 15) * 8;
            ushort hh = tobf(o);
            yhi[fi] = hh;
            ylo[fi] = tobf(o - frombf(hh));
        }
    }
}

extern "C" void kernel_launch(void* const* d_in, const int* in_sizes, int n_in,
                              void* d_out, int out_size, void* d_ws, size_t ws_size,
                              hipStream_t stream) {
    const float* x      = (const float*)d_in[0];
    const float* W_in   = (const float*)d_in[1];
    const float* conv_w = (const float*)d_in[2];
    const float* conv_b = (const float*)d_in[3];
    const float* A      = (const float*)d_in[4];
    const float* Bp     = (const float*)d_in[5];
    const float* Cp     = (const float*)d_in[6];
    const float* W_out  = (const float*)d_in[8];
    float* out = (float*)d_out;

    char* ws = (char*)d_ws;
    float* xp    = (float*)ws;                       // [0,32M): scan input
    ushort* Whi  = (ushort*)(ws + (32u << 20));      // [32,40M)
    ushort* Wlo  = (ushort*)(ws + (40u << 20));      // [40,48M)
    ushort* yghi = Whi;                              // alias after GEMM1
    ushort* yglo = Wlo;
    ushort* Wohi = (ushort*)ws;                      // [0,4M)  (xp dead after scan)
    ushort* Wolo = (ushort*)(ws + (4u << 20));       // [4,8M)
    float*  Prest = (float*)(ws + (8u << 20));       // [8,32M): split-K partials 1..3
    // x hi/lo live in d_out (8 MB) — consumed by GEMM1, overwritten by GEMM2
    ushort* xhi = (ushort*)d_out;
    ushort* xlo = xhi + (size_t)MROWS * D_MODEL;

    dim3 blk(256);
    const int n1 = NPROJ * D_MODEL / 8;   // 524288
    const int n2 = MROWS * D_MODEL / 8;   // 262144
    splitbf2_k<<<dim3((n1 + n2) / 256), blk, 0, stream>>>(
        W_in, Whi, Wlo, n1, x, xhi, xlo, n2);
    gemm1_8ph<<<dim3(16, 16), dim3(512), 0, stream>>>(xhi, xlo, Whi, Wlo, xp);
    scan_kernel<<<dim3(BSZ * NCHK * (INNER / 256)), blk, 0, stream>>>(
        xp, conv_w, conv_b, A, Bp, Cp, yghi, yglo);
    splitbf_frag<INNER><<<dim3((D_MODEL * INNER / 8) / 256), blk, 0, stream>>>(
        W_out, Wohi, Wolo, D_MODEL * INNER / 8);
    gemm_mfma_sk<128, 64, MROWS, D_MODEL, INNER, 4>
        <<<dim3(D_MODEL / 64, MROWS / 128, 4), blk, 0, stream>>>(
        yghi, yglo, Wohi, Wolo, out, Prest);
    reduce_sk<<<dim3((MROWS * D_MODEL / 4) / 256), blk, 0, stream>>>(out, Prest);
}

// Round 10
// 127.454 us; speedup vs baseline: 1.1136x; 1.1136x over previous
//
#include <hip/hip_runtime.h>
#include <hip/hip_bf16.h>

#define D_MODEL 1024
#define INNER   2048
#define NPROJ   4096   // 2*INNER
#define BSZ     2
#define LSEQ    1024
#define MROWS   (BSZ*LSEQ)  // 2048

#define CHUNK 32
#define WARM  48
#define NCHK  (LSEQ / CHUNK)   // 32

using short8   = __attribute__((ext_vector_type(8))) short;
using ushort8  = __attribute__((ext_vector_type(8))) unsigned short;
using f32x4    = __attribute__((ext_vector_type(4))) float;
typedef unsigned short ushort;

#define MFMA16(A,B,Cv) __builtin_amdgcn_mfma_f32_16x16x32_bf16(A,B,Cv,0,0,0)

__device__ __forceinline__ ushort tobf(float x) {
    return (ushort)(__builtin_bit_cast(unsigned, x) >> 16);
}
__device__ __forceinline__ float frombf(ushort h) {
    return __builtin_bit_cast(float, ((unsigned)h) << 16);
}
__device__ __forceinline__ void glds16(const void* g, void* l) {
    __builtin_amdgcn_global_load_lds((const __attribute__((address_space(1))) void*)g,
                                     (__attribute__((address_space(3))) void*)l, 16, 0, 0);
}

// f32 row-major (N x K) -> bf16 hi/lo in FRAGMENT-LINEAR order (16x32 subtiles,
// lane l = (kchunk<<4)|row holds 8 elems).
template<int K>
__device__ __forceinline__ void split_chunk(const float* __restrict__ in,
                                            ushort* __restrict__ hi,
                                            ushort* __restrict__ lo, int c) {
    int l = c & 63, sub = c >> 6;
    constexpr int KT = K / 32;
    int kt = sub % KT, rt = sub / KT;
    const float* src = in + (size_t)(rt * 16 + (l & 15)) * K + kt * 32 + (l >> 4) * 8;
    ushort8 h, lw;
#pragma unroll
    for (int j = 0; j < 8; ++j) {
        float x = src[j];
        h[j]  = tobf(x);
        lw[j] = tobf(x - frombf(h[j]));
    }
    *reinterpret_cast<ushort8*>(&hi[(size_t)c * 8]) = h;
    *reinterpret_cast<ushort8*>(&lo[(size_t)c * 8]) = lw;
}

template<int K>
__global__ __launch_bounds__(256) void splitbf_frag(const float* __restrict__ in,
                                                    ushort* __restrict__ hi,
                                                    ushort* __restrict__ lo, int nchunks) {
    int c = blockIdx.x * 256 + threadIdx.x;
    if (c >= nchunks) return;
    split_chunk<K>(in, hi, lo, c);
}

// fused: split two K=1024 matrices (W_in and x) in one launch
__global__ __launch_bounds__(256) void splitbf2_k(
    const float* __restrict__ in1, ushort* __restrict__ hi1, ushort* __restrict__ lo1, int n1,
    const float* __restrict__ in2, ushort* __restrict__ hi2, ushort* __restrict__ lo2, int n2) {
    int c = blockIdx.x * 256 + threadIdx.x;
    if (c < n1) {
        split_chunk<D_MODEL>(in1, hi1, lo1, c);
    } else {
        int cc = c - n1;
        if (cc < n2) split_chunk<D_MODEL>(in2, hi2, lo2, cc);
    }
}

// ---------------------------------------------------------------------------
// Pipelined bf16x3 GEMM: C[MROWS,NCOL] = A[MROWS,K] * B[NCOL,K]^T.
// 512 thr / 8 waves (2Mx4N), tile 128x256, BK=32, 3-buf / 2-tile prefetch.
// Per K-tile: R1{MFMA hh; read bl; 2 glds} R2{MFMA hl; read al; 2 glds} BAR
//             R3{MFMA lh; 2 glds; counted vmcnt} BAR R4{read next ah,bh}.
// Reads always issue one MFMA-cluster ahead of their consuming lgkmcnt(0),
// so LDS latency hides under the matrix pipe (2 barriers/tile total).
// ---------------------------------------------------------------------------
template<int NCOL, int K, int SPLITK, bool PARTIAL>
__global__ __launch_bounds__(512, 1) void gemm_pipe(
    const ushort* __restrict__ Agh, const ushort* __restrict__ Agl,
    const ushort* __restrict__ Bgh, const ushort* __restrict__ Bgl,
    float* __restrict__ C0, float* __restrict__ Crest)
{
    constexpr int KT = K / 32;
    constexpr int NT = KT / SPLITK;       // K-tiles per block
    __shared__ ushort Ah[3][4096], Al[3][4096];   // 128x32 bf16 per buf
    __shared__ ushort Bh[3][8192], Bl[3][8192];   // 256x32 bf16 per buf

    const int tid = threadIdx.x;
    const int wid = tid >> 6, lane = tid & 63;
    const int lm = lane & 15, lk = lane >> 4;

    constexpr int NTX = NCOL / 256;
    constexpr int NXY = NTX * (MROWS / 128);
    constexpr int CPX = NXY / 8;          // NXY % 8 == 0 -> bijective
    int lin = blockIdx.y * NTX + blockIdx.x;
    int swz = (lin & 7) * CPX + (lin >> 3);
    const int m0 = (swz / NTX) * 128, n0 = (swz % NTX) * 256;
    const int t0 = (SPLITK > 1 ? blockIdx.z : 0) * NT;
    const int wm = (wid >> 2) * 64, wn = (wid & 3) * 64;

    f32x4 acc[4][4] = {};

    auto issueB = [&](const ushort* __restrict__ src, ushort* dst, int tg, int ci) {
        int s = wid + ci * 8;
        const ushort* g = src + ((size_t)((n0 >> 4) + s) * KT + tg) * 512 + lane * 8;
        glds16(g, dst + s * 512);
    };
    auto issueA = [&](const ushort* __restrict__ src, ushort* dst, int tg) {
        const ushort* g = src + ((size_t)((m0 >> 4) + wid) * KT + tg) * 512 + lane * 8;
        glds16(g, dst + wid * 512);
    };
    auto stageTile = [&](int t, int b) {
        issueB(Bgh, &Bh[b][0], t0 + t, 0); issueB(Bgh, &Bh[b][0], t0 + t, 1);
        issueB(Bgl, &Bl[b][0], t0 + t, 0); issueB(Bgl, &Bl[b][0], t0 + t, 1);
        issueA(Agh, &Ah[b][0], t0 + t);    issueA(Agl, &Al[b][0], t0 + t);
    };

    // prologue: stage tiles 0,1; wait tile 0; preload its hh frags
    stageTile(0, 0);
    stageTile(1, 1);
    asm volatile("s_waitcnt vmcnt(6)" ::: "memory");
    __builtin_amdgcn_s_barrier();

    short8 ah[4], bh[4];
#pragma unroll
    for (int i = 0; i < 4; ++i)
        ah[i] = *reinterpret_cast<const short8*>(&Ah[0][((wm >> 4) + i) * 512 + lane * 8]);
#pragma unroll
    for (int q = 0; q < 4; ++q)
        bh[q] = *reinterpret_cast<const short8*>(&Bh[0][((wn >> 4) + q) * 512 + lane * 8]);

    int cur = 0;
    for (int t = 0; t < NT; ++t) {
        int nxt = cur + 1; if (nxt == 3) nxt = 0;
        int nx2 = cur + 2; if (nx2 >= 3) nx2 -= 3;
        const bool pf = (t + 2 < NT);
        short8 bl[4], al[4];

        // ---- R1: hh MFMA; read bl(cur); issue Bh(t+2) ----
        asm volatile("s_waitcnt lgkmcnt(0)" ::: "memory");
        __builtin_amdgcn_sched_barrier(0);
        __builtin_amdgcn_s_setprio(1);
#pragma unroll
        for (int i = 0; i < 4; ++i)
#pragma unroll
            for (int q = 0; q < 4; ++q)
                acc[i][q] = MFMA16(ah[i], bh[q], acc[i][q]);
        __builtin_amdgcn_s_setprio(0);
#pragma unroll
        for (int q = 0; q < 4; ++q)
            bl[q] = *reinterpret_cast<const short8*>(&Bl[cur][((wn >> 4) + q) * 512 + lane * 8]);
        if (pf) {
            issueB(Bgh, &Bh[nx2][0], t0 + t + 2, 0);
            issueB(Bgh, &Bh[nx2][0], t0 + t + 2, 1);
        }

        // ---- R2: hl MFMA; read al(cur); issue Bl(t+2) ----
        asm volatile("s_waitcnt lgkmcnt(0)" ::: "memory");
        __builtin_amdgcn_sched_barrier(0);
        __builtin_amdgcn_s_setprio(1);
#pragma unroll
        for (int i = 0; i < 4; ++i)
#pragma unroll
            for (int q = 0; q < 4; ++q)
                acc[i][q] = MFMA16(ah[i], bl[q], acc[i][q]);
        __builtin_amdgcn_s_setprio(0);
#pragma unroll
        for (int i = 0; i < 4; ++i)
            al[i] = *reinterpret_cast<const short8*>(&Al[cur][((wm >> 4) + i) * 512 + lane * 8]);
        if (pf) {
            issueB(Bgl, &Bl[nx2][0], t0 + t + 2, 0);
            issueB(Bgl, &Bl[nx2][0], t0 + t + 2, 1);
        }
        __builtin_amdgcn_s_barrier();   // BAR1: all waves done reading buf(t-1)

        // ---- R3: lh MFMA; issue A(t+2); counted vmcnt ----
        asm volatile("s_waitcnt lgkmcnt(0)" ::: "memory");
        __builtin_amdgcn_sched_barrier(0);
        __builtin_amdgcn_s_setprio(1);
#pragma unroll
        for (int i = 0; i < 4; ++i)
#pragma unroll
            for (int q = 0; q < 4; ++q)
                acc[i][q] = MFMA16(al[i], bh[q], acc[i][q]);
        __builtin_amdgcn_s_setprio(0);
        if (pf) {
            issueA(Agh, &Ah[nx2][0], t0 + t + 2);
            issueA(Agl, &Al[nx2][0], t0 + t + 2);
        }
        if (pf) asm volatile("s_waitcnt vmcnt(6)" ::: "memory");
        else    asm volatile("s_waitcnt vmcnt(0)" ::: "memory");
        __builtin_amdgcn_s_barrier();   // BAR2: tile t+1 fully staged

        // ---- R4: read next tile's hh frags (overlaps next R1 wait) ----
        if (t + 1 < NT) {
#pragma unroll
            for (int i = 0; i < 4; ++i)
                ah[i] = *reinterpret_cast<const short8*>(&Ah[nxt][((wm >> 4) + i) * 512 + lane * 8]);
#pragma unroll
            for (int q = 0; q < 4; ++q)
                bh[q] = *reinterpret_cast<const short8*>(&Bh[nxt][((wn >> 4) + q) * 512 + lane * 8]);
        }
        cur = nxt;
    }

    float* C = C0;
    if constexpr (PARTIAL) {
        int kz = blockIdx.z;
        if (kz != 0) C = Crest + (size_t)(kz - 1) * MROWS * NCOL;
    }
#pragma unroll
    for (int i = 0; i < 4; ++i)
#pragma unroll
        for (int j = 0; j < 4; ++j)
#pragma unroll
            for (int r = 0; r < 4; ++r) {
                int row = m0 + wm + i * 16 + lk * 4 + r;
                int col = n0 + wn + j * 16 + lm;
                C[(size_t)row * NCOL + col] = acc[i][j][r];
            }
}

// out += sum of 3 partials (out already holds partial 0)
__global__ __launch_bounds__(256) void reduce_sk(float* __restrict__ out,
                                                 const float* __restrict__ rest) {
    constexpr size_t MN = (size_t)MROWS * D_MODEL;
    size_t i = ((size_t)blockIdx.x * 256 + threadIdx.x) * 4;
    f32x4 a = *reinterpret_cast<const f32x4*>(&out[i]);
    f32x4 b = *reinterpret_cast<const f32x4*>(&rest[i]);
    f32x4 c = *reinterpret_cast<const f32x4*>(&rest[MN + i]);
    f32x4 d = *reinterpret_cast<const f32x4*>(&rest[2 * MN + i]);
    *reinterpret_cast<f32x4*>(&out[i]) = (a + b) + (c + d);
}

// Chunk-parallel fused conv + sigmoid + scan + gate; emits yg as bf16 hi/lo
// in fragment-linear order for GEMM2's A (K = INNER = 2048, KT = 64).
__global__ __launch_bounds__(256) void scan_kernel(
    const float* __restrict__ xp,
    const float* __restrict__ conv_w, const float* __restrict__ conv_b,
    const float* __restrict__ Aa, const float* __restrict__ Bp, const float* __restrict__ Cp,
    ushort* __restrict__ yhi, ushort* __restrict__ ylo)
{
    const int NB = INNER / 256;  // 8
    int tid = threadIdx.x;
    int bi = blockIdx.x;
    int b  = bi / (NCHK * NB);
    int r  = bi % (NCHK * NB);
    int ch = r / NB;
    int n  = (r % NB) * 256 + tid;

    float4 w = *reinterpret_cast<const float4*>(&conv_w[n * 4]);
    float cb = conv_b[n];
    float An[16], Bn[16], Cn[16], st[16];
#pragma unroll
    for (int i = 0; i < 16; i += 4) {
        float4 va = *reinterpret_cast<const float4*>(&Aa[n * 16 + i]);
        float4 vb = *reinterpret_cast<const float4*>(&Bp[n * 16 + i]);
        float4 vc = *reinterpret_cast<const float4*>(&Cp[n * 16 + i]);
        An[i]=va.x; An[i+1]=va.y; An[i+2]=va.z; An[i+3]=va.w;
        Bn[i]=vb.x; Bn[i+1]=vb.y; Bn[i+2]=vb.z; Bn[i+3]=vb.w;
        Cn[i]=vc.x; Cn[i+1]=vc.y; Cn[i+2]=vc.z; Cn[i+3]=vc.w;
    }
#pragma unroll
    for (int s = 0; s < 16; ++s) st[s] = 0.f;

    int out0 = ch * CHUNK;
    int lstart = (out0 >= WARM) ? (out0 - WARM) : 0;
    float u0 = 0.f, u1 = 0.f, u2 = 0.f;
    const float* xb = xp + (size_t)b * LSEQ * NPROJ;
    size_t fcol = (size_t)(n >> 5) * 512 + ((n >> 3) & 3) * 128 + (n & 7);

    for (int l = lstart; l < out0; l += 8) {
        float uv[8];
#pragma unroll
        for (int i = 0; i < 8; ++i)
            uv[i] = xb[(size_t)(l + i) * NPROJ + 2 * n];
#pragma unroll
        for (int i = 0; i < 8; ++i) {
            float ul = uv[i];
            float xc = cb + w.x * u0 + w.y * u1 + w.z * u2 + w.w * ul;
            u0 = u1; u1 = u2; u2 = ul;
            float d = 1.f / (1.f + __expf(-xc));
            float dxc = d * xc;
#pragma unroll
            for (int s = 0; s < 16; ++s)
                st[s] = (An[s] * d) * st[s] + Bn[s] * dxc;
        }
    }
    for (int lt = 0; lt < CHUNK; lt += 8) {
        float uv[8], gv[8];
#pragma unroll
        for (int i = 0; i < 8; ++i) {
            float2 ug = *reinterpret_cast<const float2*>(
                &xb[(size_t)(out0 + lt + i) * NPROJ + 2 * n]);
            uv[i] = ug.x; gv[i] = ug.y;
        }
#pragma unroll
        for (int i = 0; i < 8; ++i) {
            float ul = uv[i];
            float xc = cb + w.x * u0 + w.y * u1 + w.z * u2 + w.w * ul;
            u0 = u1; u1 = u2; u2 = ul;
            float d = 1.f / (1.f + __expf(-xc));
            float dxc = d * xc;
            float y0 = 0.f, y1 = 0.f, y2 = 0.f, y3 = 0.f;
#pragma unroll
            for (int s = 0; s < 16; s += 4) {
                st[s + 0] = (An[s + 0] * d) * st[s + 0] + Bn[s + 0] * dxc;
                st[s + 1] = (An[s + 1] * d) * st[s + 1] + Bn[s + 1] * dxc;
                st[s + 2] = (An[s + 2] * d) * st[s + 2] + Bn[s + 2] * dxc;
                st[s + 3] = (An[s + 3] * d) * st[s + 3] + Bn[s + 3] * dxc;
                y0 += st[s + 0] * Cn[s + 0];
                y1 += st[s + 1] * Cn[s + 1];
                y2 += st[s + 2] * Cn[s + 2];
                y3 += st[s + 3] * Cn[s + 3];
            }
            float y = (y0 + y1) + (y2 + y3);
            float g = 1.f / (1.f + __expf(-gv[i]));
            float o = y * g;
            int R = b * LSEQ + out0 + lt + i;
            size_t fi = ((size_t)(R >> 4) * 64) * 512 + fcol + (R & 15) * 8;
            ushort hh = tobf(o);
            yhi[fi] = hh;
            ylo[fi] = tobf(o - frombf(hh));
        }
    }
}

extern "C" void kernel_launch(void* const* d_in, const int* in_sizes, int n_in,
                              void* d_out, int out_size, void* d_ws, size_t ws_size,
                              hipStream_t stream) {
    const float* x      = (const float*)d_in[0];
    const float* W_in   = (const float*)d_in[1];
    const float* conv_w = (const float*)d_in[2];
    const float* conv_b = (const float*)d_in[3];
    const float* A      = (const float*)d_in[4];
    const float* Bp     = (const float*)d_in[5];
    const float* Cp     = (const float*)d_in[6];
    const float* W_out  = (const float*)d_in[8];
    float* out = (float*)d_out;

    char* ws = (char*)d_ws;
    float* xp    = (float*)ws;                       // [0,32M): scan input
    ushort* Whi  = (ushort*)(ws + (32u << 20));      // [32,40M)
    ushort* Wlo  = (ushort*)(ws + (40u << 20));      // [40,48M)
    ushort* yghi = Whi;                              // alias after GEMM1
    ushort* yglo = Wlo;
    ushort* Wohi = (ushort*)ws;                      // [0,4M)  (xp dead after scan)
    ushort* Wolo = (ushort*)(ws + (4u << 20));       // [4,8M)
    float*  Prest = (float*)(ws + (8u << 20));       // [8,32M): split-K partials 1..3
    // x hi/lo live in d_out (8 MB) — consumed by GEMM1, overwritten by GEMM2
    ushort* xhi = (ushort*)d_out;
    ushort* xlo = xhi + (size_t)MROWS * D_MODEL;

    dim3 blk(256);
    const int n1 = NPROJ * D_MODEL / 8;   // 524288
    const int n2 = MROWS * D_MODEL / 8;   // 262144
    splitbf2_k<<<dim3((n1 + n2) / 256), blk, 0, stream>>>(
        W_in, Whi, Wlo, n1, x, xhi, xlo, n2);
    gemm_pipe<NPROJ, D_MODEL, 1, false>
        <<<dim3(16, 16), dim3(512), 0, stream>>>(xhi, xlo, Whi, Wlo, xp, nullptr);
    scan_kernel<<<dim3(BSZ * NCHK * (INNER / 256)), blk, 0, stream>>>(
        xp, conv_w, conv_b, A, Bp, Cp, yghi, yglo);
    splitbf_frag<INNER><<<dim3((D_MODEL * INNER / 8) / 256), blk, 0, stream>>>(
        W_out, Wohi, Wolo, D_MODEL * INNER / 8);
    gemm_pipe<D_MODEL, INNER, 4, true>
        <<<dim3(4, 16, 4), dim3(512), 0, stream>>>(yghi, yglo, Wohi, Wolo, out, Prest);
    reduce_sk<<<dim3((MROWS * D_MODEL / 4) / 256), blk, 0, stream>>>(out, Prest);
}